// Round 6
// baseline (434.179 us; speedup 1.0000x reference)
//
#include <hip/hip_runtime.h>
#include <hip/hip_bf16.h>

#define DIN 32
#define DOUT 32
#define BINSHIFT 7    // 128 nodes per bin
#define BINW 128
#define NBMAX 1024    // max coarse bins (scan block = 1024 threads)
#define PK 16         // edges per thread in fused partition (block covers 4096)
#define SRCBITS 17    // packed-entry src field width (n must be <= 1<<17)

__device__ __forceinline__ float bf_lo(unsigned v) { return __uint_as_float(v << 16); }
__device__ __forceinline__ float bf_hi(unsigned v) { return __uint_as_float(v & 0xffff0000u); }
__device__ __forceinline__ unsigned f2bf_rne(float f) {
    unsigned u = __float_as_uint(f);
    return (u + 0x7fffu + ((u >> 16) & 1u)) >> 16;
}

// ---------------------------------------------------------------------------
// Coarse histograms of src and dst (bin = key >> BINSHIFT) in one read pass.
// ---------------------------------------------------------------------------
__global__ void hist_coarse_kernel(const int* __restrict__ src, const int* __restrict__ dst,
                                   int E, int* __restrict__ gcntS, int* __restrict__ gcntD) {
    __shared__ int hS[NBMAX], hD[NBMAX];
    for (int i = threadIdx.x; i < NBMAX; i += 256) { hS[i] = 0; hD[i] = 0; }
    __syncthreads();
    int stride = gridDim.x * blockDim.x;
    for (int e = blockIdx.x * blockDim.x + threadIdx.x; e < E; e += stride) {
        atomicAdd(&hS[src[e] >> BINSHIFT], 1);
        atomicAdd(&hD[dst[e] >> BINSHIFT], 1);
    }
    __syncthreads();
    for (int i = threadIdx.x; i < NBMAX; i += 256) {
        if (hS[i]) atomicAdd(&gcntS[i], hS[i]);
        if (hD[i]) atomicAdd(&gcntD[i], hD[i]);
    }
}

// ---------------------------------------------------------------------------
// Exclusive scan of both coarse histograms (single 1024-thread block).
// ---------------------------------------------------------------------------
__global__ void scan_coarse_kernel(const int* __restrict__ gcntS, const int* __restrict__ gcntD,
                                   int* __restrict__ baseS, int* __restrict__ baseD,
                                   int* __restrict__ curS, int* __restrict__ curD,
                                   int NB, int E) {
    __shared__ int s1[1024], s2[1024];
    int t = threadIdx.x;
    int a = (t < NB) ? gcntS[t] : 0;
    int c = (t < NB) ? gcntD[t] : 0;
    s1[t] = a; s2[t] = c;
    for (int o = 1; o < 1024; o <<= 1) {
        __syncthreads();
        int x = (t >= o) ? s1[t - o] : 0;
        int y = (t >= o) ? s2[t - o] : 0;
        __syncthreads();
        s1[t] += x; s2[t] += y;
    }
    __syncthreads();
    if (t < NB) {
        baseS[t] = s1[t] - a; curS[t] = s1[t] - a;
        baseD[t] = s2[t] - c; curD[t] = s2[t] - c;
    }
    if (t == 0) { baseS[NB] = E; baseD[NB] = E; }
}

// ---------------------------------------------------------------------------
// Fused partition: one read of (src,dst); writes
//   binnedS: src values binned by src>>BINSHIFT
//   binnedD: packed ((dst&127)<<SRCBITS)|src binned by dst>>BINSHIFT
// ---------------------------------------------------------------------------
__global__ void partition_both_kernel(const int* __restrict__ src, const int* __restrict__ dst,
                                      int E, int* __restrict__ curS, int* __restrict__ curD,
                                      int* __restrict__ binnedS, int* __restrict__ binnedD) {
    __shared__ int cntS[NBMAX], cntD[NBMAX];
    __shared__ int basS[NBMAX], basD[NBMAX];
    for (int i = threadIdx.x; i < NBMAX; i += 256) { cntS[i] = 0; cntD[i] = 0; }
    __syncthreads();
    int base_e = blockIdx.x * (256 * PK);
    int vs[PK], vd[PK], rkS[PK], rkD[PK];
#pragma unroll
    for (int i = 0; i < PK; ++i) {
        int e = base_e + i * 256 + threadIdx.x;
        if (e < E) {
            int s = src[e], d = dst[e];
            vs[i] = s; vd[i] = d;
            rkS[i] = atomicAdd(&cntS[s >> BINSHIFT], 1);
            rkD[i] = atomicAdd(&cntD[d >> BINSHIFT], 1);
        } else vs[i] = -1;
    }
    __syncthreads();
    for (int i = threadIdx.x; i < NBMAX; i += 256) {
        int c = cntS[i];
        basS[i] = c ? atomicAdd(&curS[i], c) : 0;
        c = cntD[i];
        basD[i] = c ? atomicAdd(&curD[i], c) : 0;
    }
    __syncthreads();
#pragma unroll
    for (int i = 0; i < PK; ++i) {
        if (vs[i] >= 0) {
            binnedS[basS[vs[i] >> BINSHIFT] + rkS[i]] = vs[i];
            binnedD[basD[vd[i] >> BINSHIFT] + rkD[i]] =
                ((vd[i] & (BINW - 1)) << SRCBITS) | vs[i];
        }
    }
}

// ---------------------------------------------------------------------------
// Per-bin src-degree count (LDS counters, bin spans 128 nodes).
// ---------------------------------------------------------------------------
__global__ void count_src_kernel(const int* __restrict__ binnedS, const int* __restrict__ baseS,
                                 int* __restrict__ degs, int n) {
    __shared__ int cnt[BINW];
    int b = blockIdx.x;
    int beg = baseS[b], end = baseS[b + 1];
    int lo = b << BINSHIFT;
    int t = threadIdx.x;
    if (t < BINW) cnt[t] = 0;
    __syncthreads();
    for (int e = beg + t; e < end; e += 256) atomicAdd(&cnt[binnedS[e] - lo], 1);
    __syncthreads();
    if (t < BINW) {
        int node = lo + t;
        if (node < n) degs[node] = cnt[t];
    }
}

// ---------------------------------------------------------------------------
// h = (x * norm_src) @ W, packed bf16x2 output. 256 = 16 rows x 16 pairs.
// ---------------------------------------------------------------------------
__global__ void transform_bf16_kernel(const float* __restrict__ x, const float* __restrict__ W,
                                      const int* __restrict__ degs,
                                      unsigned* __restrict__ h, int n) {
    __shared__ float Ws[32][33];
    __shared__ float xs[16][32];
    int pr = threadIdx.x & 15;
    int r  = threadIdx.x >> 4;

    for (int i = threadIdx.x; i < 32 * 32; i += 256) Ws[i >> 5][i & 31] = W[i];
    int row = blockIdx.x * 16 + r;
    if (row < n) {
        float2 xv = *reinterpret_cast<const float2*>(&x[(size_t)row * 32 + 2 * pr]);
        xs[r][2 * pr] = xv.x; xs[r][2 * pr + 1] = xv.y;
    }
    __syncthreads();

    if (row < n) {
        float a0 = 0.f, a1 = 0.f;
#pragma unroll
        for (int k = 0; k < 32; ++k) {
            float xv = xs[r][k];
            a0 += xv * Ws[k][2 * pr];
            a1 += xv * Ws[k][2 * pr + 1];
        }
        int d = degs[row];
        float nrm = (d > 0) ? rsqrtf((float)d) : 0.f;
        h[(size_t)row * 16 + pr] = f2bf_rne(a0 * nrm) | (f2bf_rne(a1 * nrm) << 16);
    }
}

// ---------------------------------------------------------------------------
// Fused aggregate: one block per dst bin (128 nodes). 512 threads (8 waves).
// Each 8-lane group gathers an h row (uint2 bf16x4) and ds_adds into the
// bank-swizzled LDS accumulator; in-degree counted in the same pass.
// Finalize: out = acc * rsqrt(cnt) + bias, float4 stores.
// ---------------------------------------------------------------------------
__global__ void agg_fused_kernel(const int* __restrict__ binnedD, const int* __restrict__ baseD,
                                 const uint2* __restrict__ hb, const float* __restrict__ bias,
                                 float* __restrict__ out, int n) {
    __shared__ float acc[BINW][DOUT];   // 16 KB, feature index XOR-swizzled by (r&7)<<2
    __shared__ int   cnt[BINW];
    int t = threadIdx.x;
    {
        float4* av = (float4*)acc;
        for (int i = t; i < BINW * DOUT / 4; i += 512) av[i] = float4{0.f, 0.f, 0.f, 0.f};
        if (t < BINW) cnt[t] = 0;
    }
    __syncthreads();

    int b = blockIdx.x;
    int beg = baseD[b], end = baseD[b + 1];
    int lane = t & 63;
    int w = t >> 6;      // wave 0..7
    int q = lane & 7;    // feature quad
    int g = lane >> 3;   // edge slot 0..7

    int k = beg + w * 8 + g;
    for (; k + 64 < end; k += 128) {
        unsigned p0 = (unsigned)binnedD[k];
        unsigned p1 = (unsigned)binnedD[k + 64];
        uint2 v0 = hb[(size_t)(p0 & ((1u << SRCBITS) - 1)) * 8 + q];
        uint2 v1 = hb[(size_t)(p1 & ((1u << SRCBITS) - 1)) * 8 + q];
        int r0 = (int)(p0 >> SRCBITS);
        int r1 = (int)(p1 >> SRCBITS);
        float* a0p = &acc[r0][(4 * q) ^ ((r0 & 7) << 2)];
        atomicAdd(a0p + 0, bf_lo(v0.x)); atomicAdd(a0p + 1, bf_hi(v0.x));
        atomicAdd(a0p + 2, bf_lo(v0.y)); atomicAdd(a0p + 3, bf_hi(v0.y));
        float* a1p = &acc[r1][(4 * q) ^ ((r1 & 7) << 2)];
        atomicAdd(a1p + 0, bf_lo(v1.x)); atomicAdd(a1p + 1, bf_hi(v1.x));
        atomicAdd(a1p + 2, bf_lo(v1.y)); atomicAdd(a1p + 3, bf_hi(v1.y));
        if (q == 0) { atomicAdd(&cnt[r0], 1); atomicAdd(&cnt[r1], 1); }
    }
    for (; k < end; k += 64) {
        unsigned p0 = (unsigned)binnedD[k];
        uint2 v0 = hb[(size_t)(p0 & ((1u << SRCBITS) - 1)) * 8 + q];
        int r0 = (int)(p0 >> SRCBITS);
        float* a0p = &acc[r0][(4 * q) ^ ((r0 & 7) << 2)];
        atomicAdd(a0p + 0, bf_lo(v0.x)); atomicAdd(a0p + 1, bf_hi(v0.x));
        atomicAdd(a0p + 2, bf_lo(v0.y)); atomicAdd(a0p + 3, bf_hi(v0.y));
        if (q == 0) atomicAdd(&cnt[r0], 1);
    }
    __syncthreads();

    int lo = b << BINSHIFT;
    for (int i = t; i < BINW * 8; i += 512) {
        int r = i >> 3, qq = i & 7;
        int node = lo + r;
        if (node < n) {
            int d = cnt[r];
            float nrm = (d > 0) ? rsqrtf((float)d) : 0.f;
            int s = (r & 7) << 2;
            float4 av = *reinterpret_cast<const float4*>(&acc[r][(4 * qq) ^ s]);
            float4 bv = reinterpret_cast<const float4*>(bias)[qq];
            float4 o;
            o.x = av.x * nrm + bv.x;
            o.y = av.y * nrm + bv.y;
            o.z = av.z * nrm + bv.z;
            o.w = av.w * nrm + bv.w;
            reinterpret_cast<float4*>(&out[(size_t)node * 32])[qq] = o;
        }
    }
}

// ---------------------------------------------------------------------------
// Fallback (atomic) path kernels — only if workspace too small / n too large.
// ---------------------------------------------------------------------------
__global__ void deg_kernel(const int* __restrict__ src, const int* __restrict__ dst,
                           int* __restrict__ degs, int* __restrict__ degd, int E) {
    int i = blockIdx.x * blockDim.x + threadIdx.x;
    if (i < E) {
        atomicAdd(&degs[src[i]], 1);
        atomicAdd(&degd[dst[i]], 1);
    }
}

__global__ void transform_f32_kernel(const float* __restrict__ x, const float* __restrict__ W,
                                     const int* __restrict__ degs, float* __restrict__ h, int n) {
    __shared__ float Ws[32][33];
    __shared__ float xs[8][32];
    int col = threadIdx.x & 31;
    int r   = threadIdx.x >> 5;
    for (int i = threadIdx.x; i < 32 * 32; i += 256) Ws[i >> 5][i & 31] = W[i];
    int row = blockIdx.x * 8 + r;
    xs[r][col] = (row < n) ? x[row * 32 + col] : 0.f;
    __syncthreads();
    if (row < n) {
        float acc = 0.f;
#pragma unroll
        for (int k = 0; k < 32; ++k) acc += xs[r][k] * Ws[k][col];
        int d = degs[row];
        float nrm = (d > 0) ? rsqrtf((float)d) : 0.f;
        h[row * 32 + col] = acc * nrm;
    }
}

__global__ void scatter_kernel(const int* __restrict__ src, const int* __restrict__ dst,
                               const float* __restrict__ h, float* __restrict__ out, int E) {
    int t = blockIdx.x * blockDim.x + threadIdx.x;
    int e = t >> 3;
    int q = t & 7;
    if (e < E) {
        int s = src[e];
        int d = dst[e];
        const float4 v = *reinterpret_cast<const float4*>(&h[s * 32 + q * 4]);
        float* o = &out[d * 32 + q * 4];
        atomicAdd(o + 0, v.x);
        atomicAdd(o + 1, v.y);
        atomicAdd(o + 2, v.z);
        atomicAdd(o + 3, v.w);
    }
}

__global__ void finalize_kernel(float* __restrict__ out, const int* __restrict__ degd,
                                const float* __restrict__ b, int n) {
    int t = blockIdx.x * blockDim.x + threadIdx.x;
    if (t < n * 32) {
        int row = t >> 5;
        int col = t & 31;
        int d = degd[row];
        float nrm = (d > 0) ? rsqrtf((float)d) : 0.f;
        out[t] = out[t] * nrm + b[col];
    }
}

extern "C" void kernel_launch(void* const* d_in, const int* in_sizes, int n_in,
                              void* d_out, int out_size, void* d_ws, size_t ws_size,
                              hipStream_t stream) {
    const float* x  = (const float*)d_in[0];
    const int*   ei = (const int*)d_in[1];
    const float* W  = (const float*)d_in[2];
    const float* bb = (const float*)d_in[3];
    float* out = (float*)d_out;

    const int n = in_sizes[0] / DIN;   // 100000
    const int E = in_sizes[1] / 2;     // 1600000
    const int* src = ei;
    const int* dst = ei + E;

    const int NB = (n + BINW - 1) >> BINSHIFT;   // 782

    // Workspace layout:
    //   R1: binnedS (int E)  --later-->  h (bf16 n*32)   [transform after count_src]
    //   R2: binnedD (int E)  [persists until agg_fused]
    //   degs[n] | gcntS | gcntD | baseS | baseD | curS | curD
    char* p0 = (char*)d_ws;
    char* p = p0;
    size_t szR1 = (size_t)E * sizeof(int);
    size_t szH  = (size_t)n * DOUT * sizeof(__hip_bfloat16);
    if (szH > szR1) szR1 = szH;
    szR1 = (szR1 + 15) & ~(size_t)15;
    int*      binnedS = (int*)p;
    unsigned* h       = (unsigned*)p;         p += szR1;
    int*      binnedD = (int*)p;              p += (size_t)E * sizeof(int);
    int*      degs    = (int*)p;              p += (size_t)n * sizeof(int);
    int*      gcntS   = (int*)p;              p += NBMAX * sizeof(int);
    int*      gcntD   = (int*)p;              p += NBMAX * sizeof(int);
    int*      baseS   = (int*)p;              p += (NBMAX + 1) * sizeof(int);
    int*      baseD   = (int*)p;              p += (NBMAX + 1) * sizeof(int);
    int*      curS    = (int*)p;              p += NBMAX * sizeof(int);
    int*      curD    = (int*)p;              p += NBMAX * sizeof(int);
    size_t needed = (size_t)(p - p0);

    const int partBlocks = (E + 256 * PK - 1) / (256 * PK);

    if (NB <= NBMAX && n <= (1 << SRCBITS) && ws_size >= needed) {
        hipMemsetAsync(gcntS, 0, 2 * NBMAX * sizeof(int), stream);
        hist_coarse_kernel<<<512, 256, 0, stream>>>(src, dst, E, gcntS, gcntD);
        scan_coarse_kernel<<<1, 1024, 0, stream>>>(gcntS, gcntD, baseS, baseD,
                                                   curS, curD, NB, E);
        partition_both_kernel<<<partBlocks, 256, 0, stream>>>(src, dst, E, curS, curD,
                                                              binnedS, binnedD);
        count_src_kernel<<<NB, 256, 0, stream>>>(binnedS, baseS, degs, n);
        transform_bf16_kernel<<<(n + 15) / 16, 256, 0, stream>>>(x, W, degs, h, n);
        agg_fused_kernel<<<NB, 512, 0, stream>>>(binnedD, baseD, (const uint2*)h,
                                                 bb, out, n);
    } else {
        // Fallback: atomic path. Layout: hf (f32 n*32) | degs[n] | degd[n]
        float* hf   = (float*)d_ws;
        int*   dgs  = (int*)(hf + (size_t)n * DOUT);
        int*   degd = dgs + n;
        hipMemsetAsync(dgs, 0, (size_t)2 * n * sizeof(int), stream);
        hipMemsetAsync(d_out, 0, (size_t)out_size * sizeof(float), stream);
        deg_kernel<<<(E + 255) / 256, 256, 0, stream>>>(src, dst, dgs, degd, E);
        transform_f32_kernel<<<(n + 7) / 8, 256, 0, stream>>>(x, W, dgs, hf, n);
        long long st = (long long)E * 8;
        scatter_kernel<<<(int)((st + 255) / 256), 256, 0, stream>>>(src, dst, hf, out, E);
        finalize_kernel<<<(n * 32 + 255) / 256, 256, 0, stream>>>(out, degd, bb, n);
    }
}

// Round 7
// 143.970 us; speedup vs baseline: 3.0158x; 3.0158x over previous
//
#include <hip/hip_runtime.h>
#include <hip/hip_bf16.h>

#define DIN 32
#define DOUT 32
#define NBMAX 256     // max coarse bins
#define BINSHIFT 9    // 512 nodes per bin
#define BINW 512
#define PK 8          // edges per thread in fused partition (block covers 2048)
#define SRCBITS 17    // packed-entry src field width (n must be <= 1<<17)

__device__ __forceinline__ float bf_lo(unsigned v) { return __uint_as_float(v << 16); }
__device__ __forceinline__ float bf_hi(unsigned v) { return __uint_as_float(v & 0xffff0000u); }
__device__ __forceinline__ unsigned f2bf_rne(float f) {
    unsigned u = __float_as_uint(f);
    return (u + 0x7fffu + ((u >> 16) & 1u)) >> 16;
}

// ---------------------------------------------------------------------------
// Coarse histograms of src and dst (bin = key >> BINSHIFT) in one read pass.
// ---------------------------------------------------------------------------
__global__ void hist_coarse_kernel(const int* __restrict__ src, const int* __restrict__ dst,
                                   int E, int* __restrict__ gcntS, int* __restrict__ gcntD) {
    __shared__ int hS[NBMAX], hD[NBMAX];
    for (int i = threadIdx.x; i < NBMAX; i += 256) { hS[i] = 0; hD[i] = 0; }
    __syncthreads();
    int stride = gridDim.x * blockDim.x;
    for (int e = blockIdx.x * blockDim.x + threadIdx.x; e < E; e += stride) {
        atomicAdd(&hS[src[e] >> BINSHIFT], 1);
        atomicAdd(&hD[dst[e] >> BINSHIFT], 1);
    }
    __syncthreads();
    for (int i = threadIdx.x; i < NBMAX; i += 256) {
        if (hS[i]) atomicAdd(&gcntS[i], hS[i]);
        if (hD[i]) atomicAdd(&gcntD[i], hD[i]);
    }
}

// ---------------------------------------------------------------------------
// Exclusive scan of both coarse histograms (single block); inits cursors.
// ---------------------------------------------------------------------------
__global__ void scan_coarse_kernel(const int* __restrict__ gcntS, const int* __restrict__ gcntD,
                                   int* __restrict__ baseS, int* __restrict__ baseD,
                                   int* __restrict__ curS, int* __restrict__ curD,
                                   int* __restrict__ offs, int NB, int n, int E) {
    __shared__ int s1[256], s2[256];
    int t = threadIdx.x;
    int a = (t < NB) ? gcntS[t] : 0;
    int c = (t < NB) ? gcntD[t] : 0;
    s1[t] = a; s2[t] = c;
    for (int o = 1; o < 256; o <<= 1) {
        __syncthreads();
        int x = (t >= o) ? s1[t - o] : 0;
        int y = (t >= o) ? s2[t - o] : 0;
        __syncthreads();
        s1[t] += x; s2[t] += y;
    }
    __syncthreads();
    if (t < NB) {
        baseS[t] = s1[t] - a; curS[t] = s1[t] - a;
        baseD[t] = s2[t] - c; curD[t] = s2[t] - c;
    }
    if (t == 0) { baseS[NB] = E; baseD[NB] = E; offs[n] = E; }
}

// ---------------------------------------------------------------------------
// Fused partition: one read of (src,dst); writes
//   binnedS: src values binned by src>>BINSHIFT
//   binnedD: packed ((dst&511)<<SRCBITS)|src binned by dst>>BINSHIFT
// ---------------------------------------------------------------------------
__global__ void partition_both_kernel(const int* __restrict__ src, const int* __restrict__ dst,
                                      int E, int* __restrict__ curS, int* __restrict__ curD,
                                      int* __restrict__ binnedS, int* __restrict__ binnedD) {
    __shared__ int cntS[NBMAX], cntD[NBMAX];
    __shared__ int basS[NBMAX], basD[NBMAX];
    for (int i = threadIdx.x; i < NBMAX; i += 256) { cntS[i] = 0; cntD[i] = 0; }
    __syncthreads();
    int base_e = blockIdx.x * (256 * PK);
    int vs[PK], vd[PK], rkS[PK], rkD[PK];
#pragma unroll
    for (int i = 0; i < PK; ++i) {
        int e = base_e + i * 256 + threadIdx.x;
        if (e < E) {
            int s = src[e], d = dst[e];
            vs[i] = s; vd[i] = d;
            rkS[i] = atomicAdd(&cntS[s >> BINSHIFT], 1);
            rkD[i] = atomicAdd(&cntD[d >> BINSHIFT], 1);
        } else vs[i] = -1;
    }
    __syncthreads();
    for (int i = threadIdx.x; i < NBMAX; i += 256) {
        int c = cntS[i];
        basS[i] = c ? atomicAdd(&curS[i], c) : 0;
        c = cntD[i];
        basD[i] = c ? atomicAdd(&curD[i], c) : 0;
    }
    __syncthreads();
#pragma unroll
    for (int i = 0; i < PK; ++i) {
        if (vs[i] >= 0) {
            binnedS[basS[vs[i] >> BINSHIFT] + rkS[i]] = vs[i];
            binnedD[basD[vd[i] >> BINSHIFT] + rkD[i]] =
                ((vd[i] & (BINW - 1)) << SRCBITS) | vs[i];
        }
    }
}

// ---------------------------------------------------------------------------
// Fused bin pass: blocks [0,NB) count src degrees; blocks [NB,2NB) build CSR.
// ---------------------------------------------------------------------------
__global__ void bins_fused_kernel(const int* __restrict__ binnedS, const int* __restrict__ baseS,
                                  const int* __restrict__ binnedD, const int* __restrict__ baseD,
                                  int* __restrict__ degs, int* __restrict__ offs,
                                  int* __restrict__ esrc, int n, int NB) {
    __shared__ int cnt[BINW];
    __shared__ int pscan[256];
    int t = threadIdx.x;
    if ((int)blockIdx.x < NB) {
        int b = blockIdx.x;
        int beg = baseS[b], end = baseS[b + 1];
        int lo = b << BINSHIFT;
        cnt[t] = 0; cnt[t + 256] = 0;
        __syncthreads();
        for (int e = beg + t; e < end; e += 256) atomicAdd(&cnt[binnedS[e] - lo], 1);
        __syncthreads();
        for (int i = t; i < BINW; i += 256) {
            int node = lo + i;
            if (node < n) degs[node] = cnt[i];
        }
    } else {
        int b = blockIdx.x - NB;
        int beg = baseD[b], end = baseD[b + 1];
        int lo = b << BINSHIFT;
        cnt[t] = 0; cnt[t + 256] = 0;
        __syncthreads();
        for (int e = beg + t; e < end; e += 256)
            atomicAdd(&cnt[((unsigned)binnedD[e]) >> SRCBITS], 1);
        __syncthreads();
        int c0 = cnt[2 * t], c1 = cnt[2 * t + 1];
        int pair = c0 + c1;
        pscan[t] = pair;
        for (int o = 1; o < 256; o <<= 1) {
            __syncthreads();
            int x = (t >= o) ? pscan[t - o] : 0;
            __syncthreads();
            pscan[t] += x;
        }
        __syncthreads();
        int excl = pscan[t] - pair;
        int off0 = excl, off1 = excl + c0;
        int n0 = lo + 2 * t, n1 = n0 + 1;
        if (n0 < n) offs[n0] = beg + off0;
        if (n1 < n) offs[n1] = beg + off1;
        cnt[2 * t] = off0; cnt[2 * t + 1] = off1;   // become cursors
        __syncthreads();
        for (int e = beg + t; e < end; e += 256) {
            unsigned p = (unsigned)binnedD[e];
            int r = atomicAdd(&cnt[p >> SRCBITS], 1);
            esrc[beg + r] = (int)(p & ((1u << SRCBITS) - 1));
        }
    }
}

// ---------------------------------------------------------------------------
// h = (x * norm_src) @ W, packed bf16x2 output. 256 = 16 rows x 16 pairs.
// ---------------------------------------------------------------------------
__global__ void transform_bf16_kernel(const float* __restrict__ x, const float* __restrict__ W,
                                      const int* __restrict__ degs,
                                      unsigned* __restrict__ h, int n) {
    __shared__ float Ws[32][33];
    __shared__ float xs[16][32];
    int pr = threadIdx.x & 15;
    int r  = threadIdx.x >> 4;

    for (int i = threadIdx.x; i < 32 * 32; i += 256) Ws[i >> 5][i & 31] = W[i];
    int row = blockIdx.x * 16 + r;
    if (row < n) {
        float2 xv = *reinterpret_cast<const float2*>(&x[(size_t)row * 32 + 2 * pr]);
        xs[r][2 * pr] = xv.x; xs[r][2 * pr + 1] = xv.y;
    }
    __syncthreads();

    if (row < n) {
        float a0 = 0.f, a1 = 0.f;
#pragma unroll
        for (int k = 0; k < 32; ++k) {
            float xv = xs[r][k];
            a0 += xv * Ws[k][2 * pr];
            a1 += xv * Ws[k][2 * pr + 1];
        }
        int d = degs[row];
        float nrm = (d > 0) ? rsqrtf((float)d) : 0.f;
        h[(size_t)row * 16 + pr] = f2bf_rne(a0 * nrm) | (f2bf_rne(a1 * nrm) << 16);
    }
}

// ---------------------------------------------------------------------------
// Aggregate v2: thread per (node, feature-quad). 8 threads/node, no shuffles.
// 4-deep unrolled gather loop: 4 independent esrc->hb chains in flight per
// thread (32 per wave). Deterministic fixed-order accumulation.
// ---------------------------------------------------------------------------
__global__ void aggregate_kernel(const int* __restrict__ offs, const int* __restrict__ esrc,
                                 const uint2* __restrict__ hb,
                                 const float* __restrict__ bias, float* __restrict__ out, int n) {
    int t = blockIdx.x * blockDim.x + threadIdx.x;
    int node = t >> 3;
    if (node >= n) return;
    int q = t & 7;   // feature quad

    int beg = offs[node];
    int end = offs[node + 1];

    float a0 = 0.f, a1 = 0.f, a2 = 0.f, a3 = 0.f;
    float b0 = 0.f, b1 = 0.f, b2 = 0.f, b3 = 0.f;
    int k = beg;
    for (; k + 4 <= end; k += 4) {
        int s0 = esrc[k], s1 = esrc[k + 1], s2 = esrc[k + 2], s3 = esrc[k + 3];
        uint2 v0 = hb[(size_t)s0 * 8 + q];
        uint2 v1 = hb[(size_t)s1 * 8 + q];
        uint2 v2 = hb[(size_t)s2 * 8 + q];
        uint2 v3 = hb[(size_t)s3 * 8 + q];
        a0 += bf_lo(v0.x); a1 += bf_hi(v0.x); a2 += bf_lo(v0.y); a3 += bf_hi(v0.y);
        b0 += bf_lo(v1.x); b1 += bf_hi(v1.x); b2 += bf_lo(v1.y); b3 += bf_hi(v1.y);
        a0 += bf_lo(v2.x); a1 += bf_hi(v2.x); a2 += bf_lo(v2.y); a3 += bf_hi(v2.y);
        b0 += bf_lo(v3.x); b1 += bf_hi(v3.x); b2 += bf_lo(v3.y); b3 += bf_hi(v3.y);
    }
    for (; k < end; ++k) {
        uint2 v = hb[(size_t)esrc[k] * 8 + q];
        a0 += bf_lo(v.x); a1 += bf_hi(v.x); a2 += bf_lo(v.y); a3 += bf_hi(v.y);
    }
    a0 += b0; a1 += b1; a2 += b2; a3 += b3;

    int d = end - beg;
    float nrm = (d > 0) ? rsqrtf((float)d) : 0.f;
    float4 bv = reinterpret_cast<const float4*>(bias)[q];
    float4 r;
    r.x = a0 * nrm + bv.x;
    r.y = a1 * nrm + bv.y;
    r.z = a2 * nrm + bv.z;
    r.w = a3 * nrm + bv.w;
    reinterpret_cast<float4*>(&out[(size_t)node * 32])[q] = r;
}

// ---------------------------------------------------------------------------
// Fallback (atomic) path kernels — only if workspace too small / n too large.
// ---------------------------------------------------------------------------
__global__ void deg_kernel(const int* __restrict__ src, const int* __restrict__ dst,
                           int* __restrict__ degs, int* __restrict__ degd, int E) {
    int i = blockIdx.x * blockDim.x + threadIdx.x;
    if (i < E) {
        atomicAdd(&degs[src[i]], 1);
        atomicAdd(&degd[dst[i]], 1);
    }
}

__global__ void transform_f32_kernel(const float* __restrict__ x, const float* __restrict__ W,
                                     const int* __restrict__ degs, float* __restrict__ h, int n) {
    __shared__ float Ws[32][33];
    __shared__ float xs[8][32];
    int col = threadIdx.x & 31;
    int r   = threadIdx.x >> 5;
    for (int i = threadIdx.x; i < 32 * 32; i += 256) Ws[i >> 5][i & 31] = W[i];
    int row = blockIdx.x * 8 + r;
    xs[r][col] = (row < n) ? x[row * 32 + col] : 0.f;
    __syncthreads();
    if (row < n) {
        float acc = 0.f;
#pragma unroll
        for (int k = 0; k < 32; ++k) acc += xs[r][k] * Ws[k][col];
        int d = degs[row];
        float nrm = (d > 0) ? rsqrtf((float)d) : 0.f;
        h[row * 32 + col] = acc * nrm;
    }
}

__global__ void scatter_kernel(const int* __restrict__ src, const int* __restrict__ dst,
                               const float* __restrict__ h, float* __restrict__ out, int E) {
    int t = blockIdx.x * blockDim.x + threadIdx.x;
    int e = t >> 3;
    int q = t & 7;
    if (e < E) {
        int s = src[e];
        int d = dst[e];
        const float4 v = *reinterpret_cast<const float4*>(&h[s * 32 + q * 4]);
        float* o = &out[d * 32 + q * 4];
        atomicAdd(o + 0, v.x);
        atomicAdd(o + 1, v.y);
        atomicAdd(o + 2, v.z);
        atomicAdd(o + 3, v.w);
    }
}

__global__ void finalize_kernel(float* __restrict__ out, const int* __restrict__ degd,
                                const float* __restrict__ b, int n) {
    int t = blockIdx.x * blockDim.x + threadIdx.x;
    if (t < n * 32) {
        int row = t >> 5;
        int col = t & 31;
        int d = degd[row];
        float nrm = (d > 0) ? rsqrtf((float)d) : 0.f;
        out[t] = out[t] * nrm + b[col];
    }
}

extern "C" void kernel_launch(void* const* d_in, const int* in_sizes, int n_in,
                              void* d_out, int out_size, void* d_ws, size_t ws_size,
                              hipStream_t stream) {
    const float* x  = (const float*)d_in[0];
    const int*   ei = (const int*)d_in[1];
    const float* W  = (const float*)d_in[2];
    const float* bb = (const float*)d_in[3];
    float* out = (float*)d_out;

    const int n = in_sizes[0] / DIN;   // 100000
    const int E = in_sizes[1] / 2;     // 1600000
    const int* src = ei;
    const int* dst = ei + E;

    const int NB = (n + BINW - 1) >> BINSHIFT;   // 196

    // Workspace layout:
    //   R1: binnedD (int E)  --later-->  h (bf16 n*32)   [transform after bins_fused]
    //   R2: binnedS (int E)
    //   R3: esrc   (int E)   [must NOT alias binnedS/binnedD: bins_fused races]
    //   degs[n] | offs[n+1] | gcntS | gcntD | baseS | baseD | curS | curD
    char* p0 = (char*)d_ws;
    char* p = p0;
    size_t szR1 = (size_t)E * sizeof(int);
    size_t szH  = (size_t)n * DOUT * sizeof(__hip_bfloat16);
    if (szH > szR1) szR1 = szH;
    szR1 = (szR1 + 15) & ~(size_t)15;
    int*      binnedD = (int*)p;
    unsigned* h       = (unsigned*)p;         p += szR1;
    int*      binnedS = (int*)p;              p += (size_t)E * sizeof(int);
    int*      esrc    = (int*)p;              p += (size_t)E * sizeof(int);
    int*      degs    = (int*)p;              p += (size_t)n * sizeof(int);
    int*      offs    = (int*)p;              p += (size_t)(n + 1) * sizeof(int);
    int*      gcntS   = (int*)p;              p += NBMAX * sizeof(int);
    int*      gcntD   = (int*)p;              p += NBMAX * sizeof(int);
    int*      baseS   = (int*)p;              p += (NBMAX + 1) * sizeof(int);
    int*      baseD   = (int*)p;              p += (NBMAX + 1) * sizeof(int);
    int*      curS    = (int*)p;              p += NBMAX * sizeof(int);
    int*      curD    = (int*)p;              p += NBMAX * sizeof(int);
    size_t needed = (size_t)(p - p0);

    const int partBlocks = (E + 256 * PK - 1) / (256 * PK);   // 782

    if (NB <= NBMAX && n <= (1 << SRCBITS) && ws_size >= needed) {
        hipMemsetAsync(gcntS, 0, 2 * NBMAX * sizeof(int), stream);
        hist_coarse_kernel<<<512, 256, 0, stream>>>(src, dst, E, gcntS, gcntD);
        scan_coarse_kernel<<<1, 256, 0, stream>>>(gcntS, gcntD, baseS, baseD,
                                                  curS, curD, offs, NB, n, E);
        partition_both_kernel<<<partBlocks, 256, 0, stream>>>(src, dst, E, curS, curD,
                                                              binnedS, binnedD);
        bins_fused_kernel<<<2 * NB, 256, 0, stream>>>(binnedS, baseS, binnedD, baseD,
                                                      degs, offs, esrc, n, NB);
        transform_bf16_kernel<<<(n + 15) / 16, 256, 0, stream>>>(x, W, degs, h, n);
        aggregate_kernel<<<(n * 8 + 255) / 256, 256, 0, stream>>>(
            offs, esrc, (const uint2*)h, bb, out, n);
    } else {
        // Fallback: atomic path. Layout: hf (f32 n*32) | degs[n] | degd[n]
        float* hf   = (float*)d_ws;
        int*   dgs  = (int*)(hf + (size_t)n * DOUT);
        int*   degd = dgs + n;
        hipMemsetAsync(dgs, 0, (size_t)2 * n * sizeof(int), stream);
        hipMemsetAsync(d_out, 0, (size_t)out_size * sizeof(float), stream);
        deg_kernel<<<(E + 255) / 256, 256, 0, stream>>>(src, dst, dgs, degd, E);
        transform_f32_kernel<<<(n + 7) / 8, 256, 0, stream>>>(x, W, dgs, hf, n);
        long long st = (long long)E * 8;
        scatter_kernel<<<(int)((st + 255) / 256), 256, 0, stream>>>(src, dst, hf, out, E);
        finalize_kernel<<<(n * 32 + 255) / 256, 256, 0, stream>>>(out, degd, bb, n);
    }
}

// Round 8
// 121.997 us; speedup vs baseline: 3.5589x; 1.1801x over previous
//
#include <hip/hip_runtime.h>
#include <hip/hip_bf16.h>

#define DIN 32
#define DOUT 32
#define NBMAX 256     // max coarse bins
#define BINSHIFT 9    // 512 nodes per bin
#define BINW 512
#define PK 16         // edges per thread in fused partition (block covers 4096)
#define PB (256 * PK) // edges per partition block
#define SRCBITS 17    // packed-entry src field width (n must be <= 1<<17)

__device__ __forceinline__ float bf_lo(unsigned v) { return __uint_as_float(v << 16); }
__device__ __forceinline__ float bf_hi(unsigned v) { return __uint_as_float(v & 0xffff0000u); }
__device__ __forceinline__ unsigned f2bf_rne(float f) {
    unsigned u = __float_as_uint(f);
    return (u + 0x7fffu + ((u >> 16) & 1u)) >> 16;
}

// ---------------------------------------------------------------------------
// Coarse histograms of src and dst (bin = key >> BINSHIFT) in one read pass.
// ---------------------------------------------------------------------------
__global__ void hist_coarse_kernel(const int* __restrict__ src, const int* __restrict__ dst,
                                   int E, int* __restrict__ gcntS, int* __restrict__ gcntD) {
    __shared__ int hS[NBMAX], hD[NBMAX];
    for (int i = threadIdx.x; i < NBMAX; i += 256) { hS[i] = 0; hD[i] = 0; }
    __syncthreads();
    int stride = gridDim.x * blockDim.x;
    for (int e = blockIdx.x * blockDim.x + threadIdx.x; e < E; e += stride) {
        atomicAdd(&hS[src[e] >> BINSHIFT], 1);
        atomicAdd(&hD[dst[e] >> BINSHIFT], 1);
    }
    __syncthreads();
    for (int i = threadIdx.x; i < NBMAX; i += 256) {
        if (hS[i]) atomicAdd(&gcntS[i], hS[i]);
        if (hD[i]) atomicAdd(&gcntD[i], hD[i]);
    }
}

// ---------------------------------------------------------------------------
// Exclusive scan of both coarse histograms (single block); inits cursors.
// ---------------------------------------------------------------------------
__global__ void scan_coarse_kernel(const int* __restrict__ gcntS, const int* __restrict__ gcntD,
                                   int* __restrict__ baseS, int* __restrict__ baseD,
                                   int* __restrict__ curS, int* __restrict__ curD,
                                   int* __restrict__ offs, int NB, int n, int E) {
    __shared__ int s1[256], s2[256];
    int t = threadIdx.x;
    int a = (t < NB) ? gcntS[t] : 0;
    int c = (t < NB) ? gcntD[t] : 0;
    s1[t] = a; s2[t] = c;
    for (int o = 1; o < 256; o <<= 1) {
        __syncthreads();
        int x = (t >= o) ? s1[t - o] : 0;
        int y = (t >= o) ? s2[t - o] : 0;
        __syncthreads();
        s1[t] += x; s2[t] += y;
    }
    __syncthreads();
    if (t < NB) {
        baseS[t] = s1[t] - a; curS[t] = s1[t] - a;
        baseD[t] = s2[t] - c; curD[t] = s2[t] - c;
    }
    if (t == 0) { baseS[NB] = E; baseD[NB] = E; offs[n] = E; }
}

// ---------------------------------------------------------------------------
// Fused partition with LDS staging for COALESCED binned writes.
// Rank via LDS atomics -> LDS scan of bin counts -> reserve global ranges
// (1 atomic per bin) -> scatter into bin-sorted LDS stage -> linear write-out
// (consecutive lanes hit consecutive global addresses within each bin run).
// ---------------------------------------------------------------------------
__global__ void partition_both_kernel(const int* __restrict__ src, const int* __restrict__ dst,
                                      int E, int* __restrict__ curS, int* __restrict__ curD,
                                      int* __restrict__ binnedS, int* __restrict__ binnedD) {
    __shared__ int cntS[NBMAX], cntD[NBMAX];   // counts -> lstart
    __shared__ int gbS[NBMAX], gbD[NBMAX];     // global_base - lstart
    __shared__ int stage[PB];                  // 16 KB
    __shared__ unsigned char sbin[PB];         // 4 KB
    int t = threadIdx.x;
    cntS[t] = 0; cntD[t] = 0;
    __syncthreads();

    int base_e = blockIdx.x * PB;
    int nvalid = E - base_e; if (nvalid > PB) nvalid = PB;

    int vs[PK], vd[PK], rkS[PK], rkD[PK];
#pragma unroll
    for (int i = 0; i < PK; ++i) {
        int e = base_e + i * 256 + t;
        if (e < E) {
            int s = src[e], d = dst[e];
            vs[i] = s; vd[i] = d;
            rkS[i] = atomicAdd(&cntS[s >> BINSHIFT], 1);
            rkD[i] = atomicAdd(&cntD[d >> BINSHIFT], 1);
        } else vs[i] = -1;
    }
    __syncthreads();

    // scan bin counts (inclusive, in place) -> lstart; reserve global ranges
    int cS = cntS[t], cD = cntD[t];
    for (int o = 1; o < 256; o <<= 1) {
        __syncthreads();
        int xS = (t >= o) ? cntS[t - o] : 0;
        int xD = (t >= o) ? cntD[t - o] : 0;
        __syncthreads();
        cntS[t] += xS; cntD[t] += xD;
    }
    __syncthreads();
    int lS = cntS[t] - cS, lD = cntD[t] - cD;
    int gS = cS ? atomicAdd(&curS[t], cS) : 0;
    int gD = cD ? atomicAdd(&curD[t], cD) : 0;
    gbS[t] = gS - lS; gbD[t] = gD - lD;
    __syncthreads();
    cntS[t] = lS; cntD[t] = lD;
    __syncthreads();

    // ---- round S: stage bin-sorted, then coalesced write-out ----
#pragma unroll
    for (int i = 0; i < PK; ++i) {
        if (vs[i] >= 0) {
            int b = vs[i] >> BINSHIFT;
            int slot = cntS[b] + rkS[i];
            stage[slot] = vs[i];
            sbin[slot] = (unsigned char)b;
        }
    }
    __syncthreads();
    for (int i = t; i < nvalid; i += 256)
        binnedS[gbS[sbin[i]] + i] = stage[i];
    __syncthreads();

    // ---- round D: same, packed payload ----
#pragma unroll
    for (int i = 0; i < PK; ++i) {
        if (vs[i] >= 0) {
            int b = vd[i] >> BINSHIFT;
            int slot = cntD[b] + rkD[i];
            stage[slot] = ((vd[i] & (BINW - 1)) << SRCBITS) | vs[i];
            sbin[slot] = (unsigned char)b;
        }
    }
    __syncthreads();
    for (int i = t; i < nvalid; i += 256)
        binnedD[gbD[sbin[i]] + i] = stage[i];
}

// ---------------------------------------------------------------------------
// Fused bin pass: blocks [0,NB) count src degrees; blocks [NB,2NB) build CSR.
// ---------------------------------------------------------------------------
__global__ void bins_fused_kernel(const int* __restrict__ binnedS, const int* __restrict__ baseS,
                                  const int* __restrict__ binnedD, const int* __restrict__ baseD,
                                  int* __restrict__ degs, int* __restrict__ offs,
                                  int* __restrict__ esrc, int n, int NB) {
    __shared__ int cnt[BINW];
    __shared__ int pscan[256];
    int t = threadIdx.x;
    if ((int)blockIdx.x < NB) {
        int b = blockIdx.x;
        int beg = baseS[b], end = baseS[b + 1];
        int lo = b << BINSHIFT;
        cnt[t] = 0; cnt[t + 256] = 0;
        __syncthreads();
        for (int e = beg + t; e < end; e += 256) atomicAdd(&cnt[binnedS[e] - lo], 1);
        __syncthreads();
        for (int i = t; i < BINW; i += 256) {
            int node = lo + i;
            if (node < n) degs[node] = cnt[i];
        }
    } else {
        int b = blockIdx.x - NB;
        int beg = baseD[b], end = baseD[b + 1];
        int lo = b << BINSHIFT;
        cnt[t] = 0; cnt[t + 256] = 0;
        __syncthreads();
        for (int e = beg + t; e < end; e += 256)
            atomicAdd(&cnt[((unsigned)binnedD[e]) >> SRCBITS], 1);
        __syncthreads();
        int c0 = cnt[2 * t], c1 = cnt[2 * t + 1];
        int pair = c0 + c1;
        pscan[t] = pair;
        for (int o = 1; o < 256; o <<= 1) {
            __syncthreads();
            int x = (t >= o) ? pscan[t - o] : 0;
            __syncthreads();
            pscan[t] += x;
        }
        __syncthreads();
        int excl = pscan[t] - pair;
        int off0 = excl, off1 = excl + c0;
        int n0 = lo + 2 * t, n1 = n0 + 1;
        if (n0 < n) offs[n0] = beg + off0;
        if (n1 < n) offs[n1] = beg + off1;
        cnt[2 * t] = off0; cnt[2 * t + 1] = off1;   // become cursors
        __syncthreads();
        for (int e = beg + t; e < end; e += 256) {
            unsigned p = (unsigned)binnedD[e];
            int r = atomicAdd(&cnt[p >> SRCBITS], 1);
            esrc[beg + r] = (int)(p & ((1u << SRCBITS) - 1));
        }
    }
}

// ---------------------------------------------------------------------------
// h = (x * norm_src) @ W, packed bf16x2 output. 256 = 16 rows x 16 pairs.
// ---------------------------------------------------------------------------
__global__ void transform_bf16_kernel(const float* __restrict__ x, const float* __restrict__ W,
                                      const int* __restrict__ degs,
                                      unsigned* __restrict__ h, int n) {
    __shared__ float Ws[32][33];
    __shared__ float xs[16][32];
    int pr = threadIdx.x & 15;
    int r  = threadIdx.x >> 4;

    for (int i = threadIdx.x; i < 32 * 32; i += 256) Ws[i >> 5][i & 31] = W[i];
    int row = blockIdx.x * 16 + r;
    if (row < n) {
        float2 xv = *reinterpret_cast<const float2*>(&x[(size_t)row * 32 + 2 * pr]);
        xs[r][2 * pr] = xv.x; xs[r][2 * pr + 1] = xv.y;
    }
    __syncthreads();

    if (row < n) {
        float a0 = 0.f, a1 = 0.f;
#pragma unroll
        for (int k = 0; k < 32; ++k) {
            float xv = xs[r][k];
            a0 += xv * Ws[k][2 * pr];
            a1 += xv * Ws[k][2 * pr + 1];
        }
        int d = degs[row];
        float nrm = (d > 0) ? rsqrtf((float)d) : 0.f;
        h[(size_t)row * 16 + pr] = f2bf_rne(a0 * nrm) | (f2bf_rne(a1 * nrm) << 16);
    }
}

// ---------------------------------------------------------------------------
// Aggregate: thread per (node, feature-quad). 8 threads/node, no shuffles.
// 4-deep unrolled gather loop. Deterministic fixed-order accumulation.
// ---------------------------------------------------------------------------
__global__ void aggregate_kernel(const int* __restrict__ offs, const int* __restrict__ esrc,
                                 const uint2* __restrict__ hb,
                                 const float* __restrict__ bias, float* __restrict__ out, int n) {
    int t = blockIdx.x * blockDim.x + threadIdx.x;
    int node = t >> 3;
    if (node >= n) return;
    int q = t & 7;   // feature quad

    int beg = offs[node];
    int end = offs[node + 1];

    float a0 = 0.f, a1 = 0.f, a2 = 0.f, a3 = 0.f;
    float b0 = 0.f, b1 = 0.f, b2 = 0.f, b3 = 0.f;
    int k = beg;
    for (; k + 4 <= end; k += 4) {
        int s0 = esrc[k], s1 = esrc[k + 1], s2 = esrc[k + 2], s3 = esrc[k + 3];
        uint2 v0 = hb[(size_t)s0 * 8 + q];
        uint2 v1 = hb[(size_t)s1 * 8 + q];
        uint2 v2 = hb[(size_t)s2 * 8 + q];
        uint2 v3 = hb[(size_t)s3 * 8 + q];
        a0 += bf_lo(v0.x); a1 += bf_hi(v0.x); a2 += bf_lo(v0.y); a3 += bf_hi(v0.y);
        b0 += bf_lo(v1.x); b1 += bf_hi(v1.x); b2 += bf_lo(v1.y); b3 += bf_hi(v1.y);
        a0 += bf_lo(v2.x); a1 += bf_hi(v2.x); a2 += bf_lo(v2.y); a3 += bf_hi(v2.y);
        b0 += bf_lo(v3.x); b1 += bf_hi(v3.x); b2 += bf_lo(v3.y); b3 += bf_hi(v3.y);
    }
    for (; k < end; ++k) {
        uint2 v = hb[(size_t)esrc[k] * 8 + q];
        a0 += bf_lo(v.x); a1 += bf_hi(v.x); a2 += bf_lo(v.y); a3 += bf_hi(v.y);
    }
    a0 += b0; a1 += b1; a2 += b2; a3 += b3;

    int d = end - beg;
    float nrm = (d > 0) ? rsqrtf((float)d) : 0.f;
    float4 bv = reinterpret_cast<const float4*>(bias)[q];
    float4 r;
    r.x = a0 * nrm + bv.x;
    r.y = a1 * nrm + bv.y;
    r.z = a2 * nrm + bv.z;
    r.w = a3 * nrm + bv.w;
    reinterpret_cast<float4*>(&out[(size_t)node * 32])[q] = r;
}

// ---------------------------------------------------------------------------
// Fallback (atomic) path kernels — only if workspace too small / n too large.
// ---------------------------------------------------------------------------
__global__ void deg_kernel(const int* __restrict__ src, const int* __restrict__ dst,
                           int* __restrict__ degs, int* __restrict__ degd, int E) {
    int i = blockIdx.x * blockDim.x + threadIdx.x;
    if (i < E) {
        atomicAdd(&degs[src[i]], 1);
        atomicAdd(&degd[dst[i]], 1);
    }
}

__global__ void transform_f32_kernel(const float* __restrict__ x, const float* __restrict__ W,
                                     const int* __restrict__ degs, float* __restrict__ h, int n) {
    __shared__ float Ws[32][33];
    __shared__ float xs[8][32];
    int col = threadIdx.x & 31;
    int r   = threadIdx.x >> 5;
    for (int i = threadIdx.x; i < 32 * 32; i += 256) Ws[i >> 5][i & 31] = W[i];
    int row = blockIdx.x * 8 + r;
    xs[r][col] = (row < n) ? x[row * 32 + col] : 0.f;
    __syncthreads();
    if (row < n) {
        float acc = 0.f;
#pragma unroll
        for (int k = 0; k < 32; ++k) acc += xs[r][k] * Ws[k][col];
        int d = degs[row];
        float nrm = (d > 0) ? rsqrtf((float)d) : 0.f;
        h[row * 32 + col] = acc * nrm;
    }
}

__global__ void scatter_kernel(const int* __restrict__ src, const int* __restrict__ dst,
                               const float* __restrict__ h, float* __restrict__ out, int E) {
    int t = blockIdx.x * blockDim.x + threadIdx.x;
    int e = t >> 3;
    int q = t & 7;
    if (e < E) {
        int s = src[e];
        int d = dst[e];
        const float4 v = *reinterpret_cast<const float4*>(&h[s * 32 + q * 4]);
        float* o = &out[d * 32 + q * 4];
        atomicAdd(o + 0, v.x);
        atomicAdd(o + 1, v.y);
        atomicAdd(o + 2, v.z);
        atomicAdd(o + 3, v.w);
    }
}

__global__ void finalize_kernel(float* __restrict__ out, const int* __restrict__ degd,
                                const float* __restrict__ b, int n) {
    int t = blockIdx.x * blockDim.x + threadIdx.x;
    if (t < n * 32) {
        int row = t >> 5;
        int col = t & 31;
        int d = degd[row];
        float nrm = (d > 0) ? rsqrtf((float)d) : 0.f;
        out[t] = out[t] * nrm + b[col];
    }
}

extern "C" void kernel_launch(void* const* d_in, const int* in_sizes, int n_in,
                              void* d_out, int out_size, void* d_ws, size_t ws_size,
                              hipStream_t stream) {
    const float* x  = (const float*)d_in[0];
    const int*   ei = (const int*)d_in[1];
    const float* W  = (const float*)d_in[2];
    const float* bb = (const float*)d_in[3];
    float* out = (float*)d_out;

    const int n = in_sizes[0] / DIN;   // 100000
    const int E = in_sizes[1] / 2;     // 1600000
    const int* src = ei;
    const int* dst = ei + E;

    const int NB = (n + BINW - 1) >> BINSHIFT;   // 196

    // Workspace layout:
    //   R1: binnedD (int E)  --later-->  h (bf16 n*32)   [transform after bins_fused]
    //   R2: binnedS (int E)
    //   R3: esrc   (int E)   [must NOT alias binnedS/binnedD: bins_fused races]
    //   degs[n] | offs[n+1] | gcntS | gcntD | baseS | baseD | curS | curD
    char* p0 = (char*)d_ws;
    char* p = p0;
    size_t szR1 = (size_t)E * sizeof(int);
    size_t szH  = (size_t)n * DOUT * sizeof(__hip_bfloat16);
    if (szH > szR1) szR1 = szH;
    szR1 = (szR1 + 15) & ~(size_t)15;
    int*      binnedD = (int*)p;
    unsigned* h       = (unsigned*)p;         p += szR1;
    int*      binnedS = (int*)p;              p += (size_t)E * sizeof(int);
    int*      esrc    = (int*)p;              p += (size_t)E * sizeof(int);
    int*      degs    = (int*)p;              p += (size_t)n * sizeof(int);
    int*      offs    = (int*)p;              p += (size_t)(n + 1) * sizeof(int);
    int*      gcntS   = (int*)p;              p += NBMAX * sizeof(int);
    int*      gcntD   = (int*)p;              p += NBMAX * sizeof(int);
    int*      baseS   = (int*)p;              p += (NBMAX + 1) * sizeof(int);
    int*      baseD   = (int*)p;              p += (NBMAX + 1) * sizeof(int);
    int*      curS    = (int*)p;              p += NBMAX * sizeof(int);
    int*      curD    = (int*)p;              p += NBMAX * sizeof(int);
    size_t needed = (size_t)(p - p0);

    const int partBlocks = (E + PB - 1) / PB;   // 391

    if (NB <= NBMAX && n <= (1 << SRCBITS) && ws_size >= needed) {
        hipMemsetAsync(gcntS, 0, 2 * NBMAX * sizeof(int), stream);
        hist_coarse_kernel<<<512, 256, 0, stream>>>(src, dst, E, gcntS, gcntD);
        scan_coarse_kernel<<<1, 256, 0, stream>>>(gcntS, gcntD, baseS, baseD,
                                                  curS, curD, offs, NB, n, E);
        partition_both_kernel<<<partBlocks, 256, 0, stream>>>(src, dst, E, curS, curD,
                                                              binnedS, binnedD);
        bins_fused_kernel<<<2 * NB, 256, 0, stream>>>(binnedS, baseS, binnedD, baseD,
                                                      degs, offs, esrc, n, NB);
        transform_bf16_kernel<<<(n + 15) / 16, 256, 0, stream>>>(x, W, degs, h, n);
        aggregate_kernel<<<(n * 8 + 255) / 256, 256, 0, stream>>>(
            offs, esrc, (const uint2*)h, bb, out, n);
    } else {
        // Fallback: atomic path. Layout: hf (f32 n*32) | degs[n] | degd[n]
        float* hf   = (float*)d_ws;
        int*   dgs  = (int*)(hf + (size_t)n * DOUT);
        int*   degd = dgs + n;
        hipMemsetAsync(dgs, 0, (size_t)2 * n * sizeof(int), stream);
        hipMemsetAsync(d_out, 0, (size_t)out_size * sizeof(float), stream);
        deg_kernel<<<(E + 255) / 256, 256, 0, stream>>>(src, dst, dgs, degd, E);
        transform_f32_kernel<<<(n + 7) / 8, 256, 0, stream>>>(x, W, dgs, hf, n);
        long long st = (long long)E * 8;
        scatter_kernel<<<(int)((st + 255) / 256), 256, 0, stream>>>(src, dst, hf, out, E);
        finalize_kernel<<<(n * 32 + 255) / 256, 256, 0, stream>>>(out, degd, bb, n);
    }
}

// Round 9
// 79.243 us; speedup vs baseline: 5.4791x; 1.5395x over previous
//
#include <hip/hip_runtime.h>
#include <hip/hip_bf16.h>

#define DIN 32
#define DOUT 32
#define BINSHIFT 8     // 256 nodes per bin
#define BINW 256
#define NBMAX 512      // max coarse bins
#define PTHREADS 512   // partition block threads
#define PK 8           // edges per thread in partition (block covers 4096)
#define PB (PTHREADS * PK)
#define SRCBITS 17     // packed-entry src field width (n must be <= 1<<17)
#define SRCMASK ((1u << SRCBITS) - 1u)
#define CAP_LDS 8192   // csr_agg LDS edge capacity (32 KB)

__device__ __forceinline__ float bf_lo(unsigned v) { return __uint_as_float(v << 16); }
__device__ __forceinline__ float bf_hi(unsigned v) { return __uint_as_float(v & 0xffff0000u); }
__device__ __forceinline__ unsigned f2bf_rne(float f) {
    unsigned u = __float_as_uint(f);
    return (u + 0x7fffu + ((u >> 16) & 1u)) >> 16;
}

// ---------------------------------------------------------------------------
// Cap-path init: baseX[i] = curX[i] = i*cap. Replaces memset+hist+scan.
// ---------------------------------------------------------------------------
__global__ void init_caps_kernel(int* __restrict__ baseS, int* __restrict__ baseD,
                                 int* __restrict__ curS, int* __restrict__ curD,
                                 int NB, int cap) {
    int i = threadIdx.x;
    if (i <= NB) {
        int v = i * cap;
        baseS[i] = v; baseD[i] = v;
        if (i < NB) { curS[i] = v; curD[i] = v; }
    }
}

// ---------------------------------------------------------------------------
// Hist path: coarse histograms of src and dst in one read pass.
// ---------------------------------------------------------------------------
__global__ void hist_coarse_kernel(const int* __restrict__ src, const int* __restrict__ dst,
                                   int E, int* __restrict__ gcntS, int* __restrict__ gcntD) {
    __shared__ int hS[NBMAX], hD[NBMAX];
    for (int i = threadIdx.x; i < NBMAX; i += 256) { hS[i] = 0; hD[i] = 0; }
    __syncthreads();
    int stride = gridDim.x * blockDim.x;
    for (int e = blockIdx.x * blockDim.x + threadIdx.x; e < E; e += stride) {
        atomicAdd(&hS[src[e] >> BINSHIFT], 1);
        atomicAdd(&hD[dst[e] >> BINSHIFT], 1);
    }
    __syncthreads();
    for (int i = threadIdx.x; i < NBMAX; i += 256) {
        if (hS[i]) atomicAdd(&gcntS[i], hS[i]);
        if (hD[i]) atomicAdd(&gcntD[i], hD[i]);
    }
}

// ---------------------------------------------------------------------------
// Hist path: exclusive scan of both histograms (single 512-thread block).
// ---------------------------------------------------------------------------
__global__ void scan_coarse_kernel(const int* __restrict__ gcntS, const int* __restrict__ gcntD,
                                   int* __restrict__ baseS, int* __restrict__ baseD,
                                   int* __restrict__ curS, int* __restrict__ curD,
                                   int NB, int E) {
    __shared__ int s1[NBMAX], s2[NBMAX];
    int t = threadIdx.x;
    int a = (t < NB) ? gcntS[t] : 0;
    int c = (t < NB) ? gcntD[t] : 0;
    s1[t] = a; s2[t] = c;
    for (int o = 1; o < NBMAX; o <<= 1) {
        __syncthreads();
        int x = (t >= o) ? s1[t - o] : 0;
        int y = (t >= o) ? s2[t - o] : 0;
        __syncthreads();
        s1[t] += x; s2[t] += y;
    }
    __syncthreads();
    if (t < NB) {
        baseS[t] = s1[t] - a; curS[t] = s1[t] - a;
        baseD[t] = s2[t] - c; curD[t] = s2[t] - c;
    }
    if (t == 0) { baseS[NB] = E; baseD[NB] = E; }
}

// ---------------------------------------------------------------------------
// Staged partition (512 threads): rank via LDS atomics -> LDS scan ->
// reserve global ranges (1 atomic/bin) -> bin-sorted LDS stage ->
// coalesced linear write-out. Works for both cap and hist base layouts.
// ---------------------------------------------------------------------------
__global__ void partition_both_kernel(const int* __restrict__ src, const int* __restrict__ dst,
                                      int E, int* __restrict__ curS, int* __restrict__ curD,
                                      int* __restrict__ binnedS, int* __restrict__ binnedD) {
    __shared__ int cntS[NBMAX], cntD[NBMAX];   // counts -> lstart
    __shared__ int gbS[NBMAX], gbD[NBMAX];     // global_base - lstart
    __shared__ int stage[PB];                  // 16 KB
    __shared__ unsigned short sbin[PB];        // 8 KB
    int t = threadIdx.x;
    cntS[t] = 0; cntD[t] = 0;
    __syncthreads();

    int base_e = blockIdx.x * PB;
    int nvalid = E - base_e; if (nvalid > PB) nvalid = PB;

    int vs[PK], vd[PK], rkS[PK], rkD[PK];
#pragma unroll
    for (int i = 0; i < PK; ++i) {
        int e = base_e + i * PTHREADS + t;
        if (e < E) {
            int s = src[e], d = dst[e];
            vs[i] = s; vd[i] = d;
            rkS[i] = atomicAdd(&cntS[s >> BINSHIFT], 1);
            rkD[i] = atomicAdd(&cntD[d >> BINSHIFT], 1);
        } else vs[i] = -1;
    }
    __syncthreads();

    int cS = cntS[t], cD = cntD[t];
    for (int o = 1; o < NBMAX; o <<= 1) {
        __syncthreads();
        int xS = (t >= o) ? cntS[t - o] : 0;
        int xD = (t >= o) ? cntD[t - o] : 0;
        __syncthreads();
        cntS[t] += xS; cntD[t] += xD;
    }
    __syncthreads();
    int lS = cntS[t] - cS, lD = cntD[t] - cD;
    int gS = cS ? atomicAdd(&curS[t], cS) : 0;
    int gD = cD ? atomicAdd(&curD[t], cD) : 0;
    gbS[t] = gS - lS; gbD[t] = gD - lD;
    __syncthreads();
    cntS[t] = lS; cntD[t] = lD;
    __syncthreads();

    // ---- round S ----
#pragma unroll
    for (int i = 0; i < PK; ++i) {
        if (vs[i] >= 0) {
            int b = vs[i] >> BINSHIFT;
            int slot = cntS[b] + rkS[i];
            stage[slot] = vs[i];
            sbin[slot] = (unsigned short)b;
        }
    }
    __syncthreads();
    for (int i = t; i < nvalid; i += PTHREADS)
        binnedS[gbS[sbin[i]] + i] = stage[i];
    __syncthreads();

    // ---- round D (packed payload) ----
#pragma unroll
    for (int i = 0; i < PK; ++i) {
        if (vs[i] >= 0) {
            int b = vd[i] >> BINSHIFT;
            int slot = cntD[b] + rkD[i];
            stage[slot] = ((vd[i] & (BINW - 1)) << SRCBITS) | vs[i];
            sbin[slot] = (unsigned short)b;
        }
    }
    __syncthreads();
    for (int i = t; i < nvalid; i += PTHREADS)
        binnedD[gbD[sbin[i]] + i] = stage[i];
}

// ---------------------------------------------------------------------------
// Per-bin src-degree count. Bin range = [baseS[b], endS[b]).
// ---------------------------------------------------------------------------
__global__ void count_src_kernel(const int* __restrict__ binnedS, const int* __restrict__ baseS,
                                 const int* __restrict__ endS, int* __restrict__ degs, int n) {
    __shared__ int cnt[BINW];
    int b = blockIdx.x;
    int beg = baseS[b], end = endS[b];
    int lo = b << BINSHIFT;
    int t = threadIdx.x;
    cnt[t] = 0;
    __syncthreads();
    for (int e = beg + t; e < end; e += 256) atomicAdd(&cnt[binnedS[e] - lo], 1);
    __syncthreads();
    int node = lo + t;
    if (node < n) degs[node] = cnt[t];
}

// ---------------------------------------------------------------------------
// h = (x * norm_src) @ W, packed bf16x2 output. 256 = 16 rows x 16 pairs.
// ---------------------------------------------------------------------------
__global__ void transform_bf16_kernel(const float* __restrict__ x, const float* __restrict__ W,
                                      const int* __restrict__ degs,
                                      unsigned* __restrict__ h, int n) {
    __shared__ float Ws[32][33];
    __shared__ float xs[16][32];
    int pr = threadIdx.x & 15;
    int r  = threadIdx.x >> 4;

    for (int i = threadIdx.x; i < 32 * 32; i += 256) Ws[i >> 5][i & 31] = W[i];
    int row = blockIdx.x * 16 + r;
    if (row < n) {
        float2 xv = *reinterpret_cast<const float2*>(&x[(size_t)row * 32 + 2 * pr]);
        xs[r][2 * pr] = xv.x; xs[r][2 * pr + 1] = xv.y;
    }
    __syncthreads();

    if (row < n) {
        float a0 = 0.f, a1 = 0.f;
#pragma unroll
        for (int k = 0; k < 32; ++k) {
            float xv = xs[r][k];
            a0 += xv * Ws[k][2 * pr];
            a1 += xv * Ws[k][2 * pr + 1];
        }
        int d = degs[row];
        float nrm = (d > 0) ? rsqrtf((float)d) : 0.f;
        h[(size_t)row * 16 + pr] = f2bf_rne(a0 * nrm) | (f2bf_rne(a1 * nrm) << 16);
    }
}

// ---------------------------------------------------------------------------
// Fused CSR+aggregate: one block per dst bin (256 nodes), 1024 threads.
// Per chunk (<= CAP_LDS edges): count (LDS int atomics) -> 256-scan ->
// rank-scatter src ids into LDS -> gather hb + accumulate in registers.
// Finalize: out = acc * rsqrt(indeg) + bias. No global CSR, no f32 atomics.
// ---------------------------------------------------------------------------
__global__ void csr_agg_kernel(const int* __restrict__ binnedD, const int* __restrict__ baseD,
                               const int* __restrict__ endD, const uint2* __restrict__ hb,
                               const float* __restrict__ bias, float* __restrict__ out, int n) {
    __shared__ int cnt[BINW];
    __shared__ int start[BINW];
    __shared__ int cur[BINW];
    __shared__ int lesrc[CAP_LDS];   // 32 KB

    int t = threadIdx.x;
    int b = blockIdx.x;
    int beg = baseD[b], end = endD[b];
    int lo = b << BINSHIFT;
    int q  = t & 7;     // feature quad
    int ng = t >> 3;    // node group 0..127; units: ng, ng+128

    float4 a0 = {0.f, 0.f, 0.f, 0.f};
    float4 a1 = {0.f, 0.f, 0.f, 0.f};
    int d0 = 0, d1 = 0;

    for (int cb = beg; cb < end; cb += CAP_LDS) {
        int ce = cb + CAP_LDS; if (ce > end) ce = end;
        if (t < BINW) cnt[t] = 0;
        __syncthreads();
        for (int e = cb + t; e < ce; e += 1024)
            atomicAdd(&cnt[((unsigned)binnedD[e]) >> SRCBITS], 1);
        __syncthreads();
        // exclusive scan of cnt into start (first 256 threads)
        if (t < BINW) start[t] = cnt[t];
        __syncthreads();
        for (int o = 1; o < BINW; o <<= 1) {
            int x = 0;
            if (t < BINW && t >= o) x = start[t - o];
            __syncthreads();
            if (t < BINW) start[t] += x;
            __syncthreads();
        }
        if (t < BINW) { int excl = start[t] - cnt[t]; start[t] = excl; cur[t] = excl; }
        __syncthreads();
        // rank-scatter into LDS
        for (int e = cb + t; e < ce; e += 1024) {
            unsigned p = (unsigned)binnedD[e];
            int r = atomicAdd(&cur[p >> SRCBITS], 1);
            lesrc[r] = (int)(p & SRCMASK);
        }
        __syncthreads();
        // gather + accumulate, unit 0 (node ng)
        {
            int kb = start[ng], kc = cnt[ng];
            d0 += kc;
            int k = kb, ke = kb + kc;
            for (; k + 4 <= ke; k += 4) {
                int s0 = lesrc[k], s1 = lesrc[k + 1], s2 = lesrc[k + 2], s3 = lesrc[k + 3];
                uint2 v0 = hb[(size_t)s0 * 8 + q];
                uint2 v1 = hb[(size_t)s1 * 8 + q];
                uint2 v2 = hb[(size_t)s2 * 8 + q];
                uint2 v3 = hb[(size_t)s3 * 8 + q];
                a0.x += bf_lo(v0.x); a0.y += bf_hi(v0.x); a0.z += bf_lo(v0.y); a0.w += bf_hi(v0.y);
                a0.x += bf_lo(v1.x); a0.y += bf_hi(v1.x); a0.z += bf_lo(v1.y); a0.w += bf_hi(v1.y);
                a0.x += bf_lo(v2.x); a0.y += bf_hi(v2.x); a0.z += bf_lo(v2.y); a0.w += bf_hi(v2.y);
                a0.x += bf_lo(v3.x); a0.y += bf_hi(v3.x); a0.z += bf_lo(v3.y); a0.w += bf_hi(v3.y);
            }
            for (; k < ke; ++k) {
                uint2 v = hb[(size_t)lesrc[k] * 8 + q];
                a0.x += bf_lo(v.x); a0.y += bf_hi(v.x); a0.z += bf_lo(v.y); a0.w += bf_hi(v.y);
            }
        }
        // unit 1 (node ng+128)
        {
            int nl = ng + 128;
            int kb = start[nl], kc = cnt[nl];
            d1 += kc;
            int k = kb, ke = kb + kc;
            for (; k + 4 <= ke; k += 4) {
                int s0 = lesrc[k], s1 = lesrc[k + 1], s2 = lesrc[k + 2], s3 = lesrc[k + 3];
                uint2 v0 = hb[(size_t)s0 * 8 + q];
                uint2 v1 = hb[(size_t)s1 * 8 + q];
                uint2 v2 = hb[(size_t)s2 * 8 + q];
                uint2 v3 = hb[(size_t)s3 * 8 + q];
                a1.x += bf_lo(v0.x); a1.y += bf_hi(v0.x); a1.z += bf_lo(v0.y); a1.w += bf_hi(v0.y);
                a1.x += bf_lo(v1.x); a1.y += bf_hi(v1.x); a1.z += bf_lo(v1.y); a1.w += bf_hi(v1.y);
                a1.x += bf_lo(v2.x); a1.y += bf_hi(v2.x); a1.z += bf_lo(v2.y); a1.w += bf_hi(v2.y);
                a1.x += bf_lo(v3.x); a1.y += bf_hi(v3.x); a1.z += bf_lo(v3.y); a1.w += bf_hi(v3.y);
            }
            for (; k < ke; ++k) {
                uint2 v = hb[(size_t)lesrc[k] * 8 + q];
                a1.x += bf_lo(v.x); a1.y += bf_hi(v.x); a1.z += bf_lo(v.y); a1.w += bf_hi(v.y);
            }
        }
        __syncthreads();   // protect lesrc/cnt before next chunk
    }

    float4 bv = reinterpret_cast<const float4*>(bias)[q];
    int n0 = lo + ng;
    if (n0 < n) {
        float nrm = (d0 > 0) ? rsqrtf((float)d0) : 0.f;
        float4 r;
        r.x = a0.x * nrm + bv.x; r.y = a0.y * nrm + bv.y;
        r.z = a0.z * nrm + bv.z; r.w = a0.w * nrm + bv.w;
        reinterpret_cast<float4*>(&out[(size_t)n0 * 32])[q] = r;
    }
    int n1 = lo + ng + 128;
    if (n1 < n) {
        float nrm = (d1 > 0) ? rsqrtf((float)d1) : 0.f;
        float4 r;
        r.x = a1.x * nrm + bv.x; r.y = a1.y * nrm + bv.y;
        r.z = a1.z * nrm + bv.z; r.w = a1.w * nrm + bv.w;
        reinterpret_cast<float4*>(&out[(size_t)n1 * 32])[q] = r;
    }
}

// ---------------------------------------------------------------------------
// Fallback (atomic) path kernels — only if workspace too small / n too large.
// ---------------------------------------------------------------------------
__global__ void deg_kernel(const int* __restrict__ src, const int* __restrict__ dst,
                           int* __restrict__ degs, int* __restrict__ degd, int E) {
    int i = blockIdx.x * blockDim.x + threadIdx.x;
    if (i < E) {
        atomicAdd(&degs[src[i]], 1);
        atomicAdd(&degd[dst[i]], 1);
    }
}

__global__ void transform_f32_kernel(const float* __restrict__ x, const float* __restrict__ W,
                                     const int* __restrict__ degs, float* __restrict__ h, int n) {
    __shared__ float Ws[32][33];
    __shared__ float xs[8][32];
    int col = threadIdx.x & 31;
    int r   = threadIdx.x >> 5;
    for (int i = threadIdx.x; i < 32 * 32; i += 256) Ws[i >> 5][i & 31] = W[i];
    int row = blockIdx.x * 8 + r;
    xs[r][col] = (row < n) ? x[row * 32 + col] : 0.f;
    __syncthreads();
    if (row < n) {
        float acc = 0.f;
#pragma unroll
        for (int k = 0; k < 32; ++k) acc += xs[r][k] * Ws[k][col];
        int d = degs[row];
        float nrm = (d > 0) ? rsqrtf((float)d) : 0.f;
        h[row * 32 + col] = acc * nrm;
    }
}

__global__ void scatter_kernel(const int* __restrict__ src, const int* __restrict__ dst,
                               const float* __restrict__ h, float* __restrict__ out, int E) {
    int t = blockIdx.x * blockDim.x + threadIdx.x;
    int e = t >> 3;
    int q = t & 7;
    if (e < E) {
        int s = src[e];
        int d = dst[e];
        const float4 v = *reinterpret_cast<const float4*>(&h[s * 32 + q * 4]);
        float* o = &out[d * 32 + q * 4];
        atomicAdd(o + 0, v.x);
        atomicAdd(o + 1, v.y);
        atomicAdd(o + 2, v.z);
        atomicAdd(o + 3, v.w);
    }
}

__global__ void finalize_kernel(float* __restrict__ out, const int* __restrict__ degd,
                                const float* __restrict__ b, int n) {
    int t = blockIdx.x * blockDim.x + threadIdx.x;
    if (t < n * 32) {
        int row = t >> 5;
        int col = t & 31;
        int d = degd[row];
        float nrm = (d > 0) ? rsqrtf((float)d) : 0.f;
        out[t] = out[t] * nrm + b[col];
    }
}

extern "C" void kernel_launch(void* const* d_in, const int* in_sizes, int n_in,
                              void* d_out, int out_size, void* d_ws, size_t ws_size,
                              hipStream_t stream) {
    const float* x  = (const float*)d_in[0];
    const int*   ei = (const int*)d_in[1];
    const float* W  = (const float*)d_in[2];
    const float* bb = (const float*)d_in[3];
    float* out = (float*)d_out;

    const int n = in_sizes[0] / DIN;   // 100000
    const int E = in_sizes[1] / 2;     // 1600000
    const int* src = ei;
    const int* dst = ei + E;

    const int NB = (n + BINW - 1) >> BINSHIFT;   // 391

    // cap for fixed-capacity bins: 1.5x mean, rounded to 256
    int cap = (int)((((long long)E / NB) * 3 / 2 + 255) & ~255LL);
    if (cap < 1024) cap = 1024;

    size_t szH      = ((size_t)n * DOUT * sizeof(__hip_bfloat16) + 15) & ~(size_t)15;
    size_t szBinE   = ((size_t)E * sizeof(int) + 15) & ~(size_t)15;
    size_t szBinCap = ((size_t)NB * cap * sizeof(int) + PB * sizeof(int) + 15) & ~(size_t)15;
    size_t szSmall  = (size_t)n * sizeof(int) + 6 * (NBMAX + 1) * sizeof(int) + 64;

    // common small-array layout appended after the two big regions
    auto layout = [&](size_t szBin, char* p0, int** binnedS, unsigned** h, int** binnedD,
                      int** degs, int** gcntS, int** gcntD, int** baseS, int** baseD,
                      int** curS, int** curD) -> size_t {
        char* p = p0;
        size_t szR1 = (szBin > szH) ? szBin : szH;   // binnedS aliases h
        *binnedS = (int*)p; *h = (unsigned*)p;      p += szR1;
        *binnedD = (int*)p;                         p += szBin;
        *degs    = (int*)p;                         p += (size_t)n * sizeof(int);
        *gcntS   = (int*)p;                         p += NBMAX * sizeof(int);
        *gcntD   = (int*)p;                         p += NBMAX * sizeof(int);
        *baseS   = (int*)p;                         p += (NBMAX + 1) * sizeof(int);
        *baseD   = (int*)p;                         p += (NBMAX + 1) * sizeof(int);
        *curS    = (int*)p;                         p += NBMAX * sizeof(int);
        *curD    = (int*)p;                         p += NBMAX * sizeof(int);
        return (size_t)(p - p0);
    };

    int *binnedS, *binnedD, *degs, *gcntS, *gcntD, *baseS, *baseD, *curS, *curD;
    unsigned* h;

    size_t needed_cap  = szBinCap * 2 + szSmall + ((szBinCap > szH) ? 0 : (szH - szBinCap));
    // (exact value recomputed by layout below; the estimate above is conservative)

    const int partBlocks = (E + PB - 1) / PB;

    bool ok = (NB <= NBMAX) && (n <= (1 << SRCBITS));

    if (ok) {
        // try cap path first
        size_t need = layout(szBinCap, (char*)d_ws, &binnedS, &h, &binnedD, &degs,
                             &gcntS, &gcntD, &baseS, &baseD, &curS, &curD);
        if (need <= ws_size) {
            init_caps_kernel<<<1, NBMAX, 0, stream>>>(baseS, baseD, curS, curD, NB, cap);
            partition_both_kernel<<<partBlocks, PTHREADS, 0, stream>>>(src, dst, E, curS, curD,
                                                                       binnedS, binnedD);
            count_src_kernel<<<NB, 256, 0, stream>>>(binnedS, baseS, curS, degs, n);
            transform_bf16_kernel<<<(n + 15) / 16, 256, 0, stream>>>(x, W, degs, h, n);
            csr_agg_kernel<<<NB, 1024, 0, stream>>>(binnedD, baseD, curD, (const uint2*)h,
                                                    bb, out, n);
            return;
        }
        // hist path (exact bins)
        need = layout(szBinE, (char*)d_ws, &binnedS, &h, &binnedD, &degs,
                      &gcntS, &gcntD, &baseS, &baseD, &curS, &curD);
        if (need <= ws_size) {
            hipMemsetAsync(gcntS, 0, 2 * NBMAX * sizeof(int), stream);
            hist_coarse_kernel<<<512, 256, 0, stream>>>(src, dst, E, gcntS, gcntD);
            scan_coarse_kernel<<<1, NBMAX, 0, stream>>>(gcntS, gcntD, baseS, baseD,
                                                        curS, curD, NB, E);
            partition_both_kernel<<<partBlocks, PTHREADS, 0, stream>>>(src, dst, E, curS, curD,
                                                                       binnedS, binnedD);
            count_src_kernel<<<NB, 256, 0, stream>>>(binnedS, baseS, curS, degs, n);
            transform_bf16_kernel<<<(n + 15) / 16, 256, 0, stream>>>(x, W, degs, h, n);
            csr_agg_kernel<<<NB, 1024, 0, stream>>>(binnedD, baseD, curD, (const uint2*)h,
                                                    bb, out, n);
            return;
        }
    }

    // Fallback: atomic path. Layout: hf (f32 n*32) | degs[n] | degd[n]
    {
        float* hf   = (float*)d_ws;
        int*   dgs  = (int*)(hf + (size_t)n * DOUT);
        int*   degd = dgs + n;
        hipMemsetAsync(dgs, 0, (size_t)2 * n * sizeof(int), stream);
        hipMemsetAsync(d_out, 0, (size_t)out_size * sizeof(float), stream);
        deg_kernel<<<(E + 255) / 256, 256, 0, stream>>>(src, dst, dgs, degd, E);
        transform_f32_kernel<<<(n + 7) / 8, 256, 0, stream>>>(x, W, dgs, hf, n);
        long long st = (long long)E * 8;
        scatter_kernel<<<(int)((st + 255) / 256), 256, 0, stream>>>(src, dst, hf, out, E);
        finalize_kernel<<<(n * 32 + 255) / 256, 256, 0, stream>>>(out, degd, bb, n);
    }
}